// Round 11
// baseline (191.871 us; speedup 1.0000x reference)
//
#include <hip/hip_runtime.h>

// LengthRegulator: B=32, T=512, D=384, DUR_MAX=8, L = 512*7 = 3584
// R11 = R10 shell (single dispatch, 2048 blocks, hoisted x loads, 9-int cum
// exchange, balanced zero tail) with the content write path replaced by
// LDS-staged CONTIGUOUS span writes: each block stages its 8 rows in LDS
// (12 KiB) and streams frames [cum[r0-1], cum[r0+7]) as one dense,
// full-wave, line-aligned sequential store stream (every byte exactly once,
// no predicated duplicate stores). Row lookup = 8-way compare per f4.

#define B_DIM 32
#define T_DIM 512
#define D_DIM 384
#define L_DIM 3584
#define VEC 96                          // f32x4 per row
#define RPB 8                           // rows per block
#define CHUNKS (T_DIM / RPB)            // 64
#define BLOCKS (B_DIM * CHUNKS)         // 2048 = 8 per CU

typedef float f32x4 __attribute__((ext_vector_type(4)));

__global__ void __launch_bounds__(256)
lr_fused(const f32x4* __restrict__ x, const int* __restrict__ dur,
         f32x4* __restrict__ out, float* __restrict__ mel_out) {
    const int blk  = blockIdx.x;
    const int b    = blk >> 6;          // /CHUNKS
    const int c    = blk & 63;
    const int t    = threadIdx.x;       // 0..255
    const int lane = t & 63;
    const int wv   = t >> 6;            // 0..3
    const int r0   = c * RPB;

    // ---- issue x row loads first (latency overlapped with scan)
    const f32x4* xb = x + (size_t)(b * T_DIM + r0) * VEC;
    const f32x4 a0 = xb[t];
    const f32x4 a1 = xb[t + 256];
    const f32x4 a2 = xb[t + 512];

    // ---- full-batch scan: thread t owns tokens 2t, 2t+1 (L2-hot)
    const int2 dd = ((const int2*)(dur + b * T_DIM))[t];
    const int e0 = dd.x > 1 ? dd.x : 1;
    const int e1 = dd.y > 1 ? dd.y : 1;

    int val = e0 + e1;                  // wave inclusive scan of pair-sums
    #pragma unroll
    for (int off = 1; off < 64; off <<= 1) {
        int n = __shfl_up(val, off, 64);
        if (lane >= off) val += n;
    }

    __shared__ int   wsum[4];
    __shared__ int   s[RPB + 1];        // cum[r0-1 .. r0+7]
    __shared__ f32x4 lx[RPB * VEC];     // 12 KiB staged rows
    if (lane == 63) wsum[wv] = val;
    __syncthreads();

    int base = 0, tot = 0;
    #pragma unroll
    for (int i = 0; i < 4; ++i) {
        int w = wsum[i];
        tot += w;
        if (i < wv) base += w;
    }
    const int cum1 = val + base;        // cum of token 2t+1
    const int cum0 = cum1 - e1;         // cum of token 2t

    // ---- 9-value cum exchange: threads 4c..4c+3 own tokens r0..r0+7
    if ((t >> 2) == c) {
        const int j = t & 3;
        s[2 * j + 1] = cum0;
        s[2 * j + 2] = cum1;
    }
    if (t == 4 * c - 1) s[0] = cum1;    // predecessor cum (token r0-1)
    if (c == 0 && t == 0) s[0] = 0;

    // ---- stage rows into LDS (loads already in flight)
    lx[t]       = a0;
    lx[t + 256] = a1;
    lx[t + 512] = a2;
    __syncthreads();

    const int mel = tot;
    if (c == 0 && t == 0)
        mel_out[b] = (float)mel;

    f32x4* outb = out + (size_t)b * L_DIM * VEC;

    // ---- contiguous span write: every byte once, full-wave sequential
    {
        const int s0 = s[0], s1 = s[1], s2 = s[2], s3 = s[3], s4 = s[4],
                  s5 = s[5], s6 = s[6], s7 = s[7], s8 = s[8];
        const int span4 = (s8 - s0) * VEC;      // 768..5376 f4
        f32x4* ob = outb + (size_t)s0 * VEC;
        for (int v = t; v < span4; v += 256) {
            const int fr = v / VEC;             // const divisor (96)
            const int w  = v - fr * VEC;
            const int fa = s0 + fr;
            const int r  = (fa >= s1) + (fa >= s2) + (fa >= s3) + (fa >= s4)
                         + (fa >= s5) + (fa >= s6) + (fa >= s7);
            ob[v] = lx[r * VEC + w];            // bank-clean LDS read
        }
    }

    // ---- balanced zero tail: 1/64 slice of [mel, L)
    const int tailspan = L_DIM - mel;   // 0..3072
    const int lo = mel + ((tailspan * c) >> 6);
    const int hi = mel + ((tailspan * (c + 1)) >> 6);
    const int n4 = (hi - lo) * VEC;
    const f32x4 z = (f32x4)0.f;
    f32x4* ob = outb + (size_t)lo * VEC;
    for (int v = t; v < n4; v += 256)
        ob[v] = z;
}

extern "C" void kernel_launch(void* const* d_in, const int* in_sizes, int n_in,
                              void* d_out, int out_size, void* d_ws, size_t ws_size,
                              hipStream_t stream) {
    const float* x   = (const float*)d_in[0];
    const int*   dur = (const int*)d_in[1];

    float* out     = (float*)d_out;
    float* mel_out = out + (size_t)B_DIM * L_DIM * D_DIM; // mel_len tail as f32

    lr_fused<<<dim3(BLOCKS), dim3(256), 0, stream>>>(
        (const f32x4*)x, dur, (f32x4*)out, mel_out);
}